// Round 2
// baseline (197.745 us; speedup 1.0000x reference)
//
#include <hip/hip_runtime.h>
#include <math.h>

#define NPTS 21
#define FLB  63          // floats per batch per tensor (21*3)
#define BPB  64          // batches per block = one batch per thread
#define THREADS 64       // single wave -> __syncthreads is intra-wave (no s_barrier)

__global__ void pa_init(float* out) {
    if (threadIdx.x == 0 && blockIdx.x == 0) out[0] = 0.0f;
}

__global__ __launch_bounds__(THREADS, 4)
void pa_mpjpe(const float* __restrict__ pred,
              const float* __restrict__ targ,
              float* __restrict__ out,
              int B, float inv_total)
{
    // stride-63 layout: odd stride -> at most 2-way LDS bank aliasing (free)
    __shared__ __align__(16) float sbuf[BPB * FLB];   // 16128 B -> ~10 blocks/CU

    const int tid  = threadIdx.x;
    const int b0   = blockIdx.x * BPB;
    const int nb   = (B - b0 < BPB) ? (B - b0) : BPB;
    const int nflt = nb * FLB;
    const int nvec = nflt >> 2;          // 64*63 divisible by 4 -> no scalar tail for full blocks

    // ---- stage PRED chunk into LDS (coalesced float4; block base 16B-aligned) ----
    {
        const float4* g = (const float4*)(pred + (size_t)b0 * FLB);
        float4* s = (float4*)sbuf;
        for (int i = tid; i < nvec; i += THREADS) s[i] = g[i];
        const float* gf = pred + (size_t)b0 * FLB;
        for (int i = (nvec << 2) + tid; i < nflt; i += THREADS) sbuf[i] = gf[i];
    }
    __syncthreads();

    // ---- pred -> registers, accumulate raw moments ----
    float y[NPTS][3];
    float sy0 = 0.f, sy1 = 0.f, sy2 = 0.f, syy = 0.f;
    const int base = tid * FLB;
    #pragma unroll
    for (int n = 0; n < NPTS; ++n) {
        float a = sbuf[base + 3*n + 0];
        float b = sbuf[base + 3*n + 1];
        float c = sbuf[base + 3*n + 2];
        y[n][0] = a; y[n][1] = b; y[n][2] = c;
        sy0 += a; sy1 += b; sy2 += c;
        syy = fmaf(a, a, fmaf(b, b, fmaf(c, c, syy)));
    }
    __syncthreads();

    // ---- stage TARG chunk into the SAME LDS buffer ----
    {
        const float4* g = (const float4*)(targ + (size_t)b0 * FLB);
        float4* s = (float4*)sbuf;
        for (int i = tid; i < nvec; i += THREADS) s[i] = g[i];
        const float* gf = targ + (size_t)b0 * FLB;
        for (int i = (nvec << 2) + tid; i < nflt; i += THREADS) sbuf[i] = gf[i];
    }
    __syncthreads();

    // ---- targ stats + raw cross-covariance M[i][j] = sum_n x_i * y_j ----
    float sx0 = 0.f, sx1 = 0.f, sx2 = 0.f;
    float m00=0,m01=0,m02=0, m10=0,m11=0,m12=0, m20=0,m21=0,m22=0;
    #pragma unroll
    for (int n = 0; n < NPTS; ++n) {
        float a = sbuf[base + 3*n + 0];
        float b = sbuf[base + 3*n + 1];
        float c = sbuf[base + 3*n + 2];
        sx0 += a; sx1 += b; sx2 += c;
        float u = y[n][0], v = y[n][1], w = y[n][2];
        m00 = fmaf(a,u,m00); m01 = fmaf(a,v,m01); m02 = fmaf(a,w,m02);
        m10 = fmaf(b,u,m10); m11 = fmaf(b,v,m11); m12 = fmaf(b,w,m12);
        m20 = fmaf(c,u,m20); m21 = fmaf(c,v,m21); m22 = fmaf(c,w,m22);
    }

    const float invN = 1.0f / (float)NPTS;
    float mux0 = sx0*invN, mux1 = sx1*invN, mux2 = sx2*invN;
    float muy0 = sy0*invN, muy1 = sy1*invN, muy2 = sy2*invN;
    float ny2  = syy - (sy0*sy0 + sy1*sy1 + sy2*sy2) * invN;   // ||Y0||_F^2
    // centered cross-cov (rows: targ dims i, cols: pred dims j)
    float c00 = m00 - sx0*sy0*invN, c01 = m01 - sx0*sy1*invN, c02 = m02 - sx0*sy2*invN;
    float c10 = m10 - sx1*sy0*invN, c11 = m11 - sx1*sy1*invN, c12 = m12 - sx1*sy2*invN;
    float c20 = m20 - sx2*sy0*invN, c21 = m21 - sx2*sy1*invN, c22 = m22 - sx2*sy2*invN;

    // ---- orthogonal polar factor of A = Mc^T via det-scaled Newton ----
    // A = V S U^T => polar Q = V U^T (reference's rotation, reflection allowed),
    // tr(P) = sum of singular values = <Q, A>_F.  Scale-invariant: skip norms.
    float q00=c00, q01=c10, q02=c20,
          q10=c01, q11=c11, q12=c21,
          q20=c02, q21=c12, q22=c22;
    #pragma unroll
    for (int it = 0; it < 8; ++it) {
        float C00 = q11*q22 - q12*q21;
        float C01 = q12*q20 - q10*q22;
        float C02 = q10*q21 - q11*q20;
        float C10 = q02*q21 - q01*q22;
        float C11 = q00*q22 - q02*q20;
        float C12 = q01*q20 - q00*q21;
        float C20 = q01*q12 - q02*q11;
        float C21 = q02*q10 - q00*q12;
        float C22 = q00*q11 - q01*q10;
        float det = q00*C00 + q01*C01 + q02*C02;
        float ad  = fmaxf(fabsf(det), 1e-30f);
        float sdet = copysignf(ad, det);
        float g  = __expf(0.333333333f * __logf(ad));   // |det|^{1/3}
        float ha = 0.5f / g;                            // 0.5 * gamma
        float hb = 0.5f * g / sdet;                     // 0.5 * gamma^{-1} / det
        q00 = ha*q00 + hb*C00; q01 = ha*q01 + hb*C01; q02 = ha*q02 + hb*C02;
        q10 = ha*q10 + hb*C10; q11 = ha*q11 + hb*C11; q12 = ha*q12 + hb*C12;
        q20 = ha*q20 + hb*C20; q21 = ha*q21 + hb*C21; q22 = ha*q22 + hb*C22;
    }

    // tr(P) = <Q, A>_F with A = Mc^T  (sum of singular values of Mc)
    float trP = q00*c00 + q01*c10 + q02*c20
              + q10*c01 + q11*c11 + q12*c21
              + q20*c02 + q21*c12 + q22*c22;
    // Z_j = (trP/||Y0||^2) * sum_i (y_i - muY_i) Q_ij + muX_j   (normX cancels)
    float k = trP / ny2;
    float r00=k*q00, r01=k*q01, r02=k*q02;
    float r10=k*q10, r11=k*q11, r12=k*q12;
    float r20=k*q20, r21=k*q21, r22=k*q22;

    // ---- per-joint error (targ still in LDS) ----
    float errsum = 0.0f;
    #pragma unroll
    for (int n = 0; n < NPTS; ++n) {
        float xa = sbuf[base + 3*n + 0];
        float xb = sbuf[base + 3*n + 1];
        float xc = sbuf[base + 3*n + 2];
        float u = y[n][0] - muy0, v = y[n][1] - muy1, w = y[n][2] - muy2;
        float z0 = fmaf(u, r00, fmaf(v, r10, fmaf(w, r20, mux0))) - xa;
        float z1 = fmaf(u, r01, fmaf(v, r11, fmaf(w, r21, mux1))) - xb;
        float z2 = fmaf(u, r02, fmaf(v, r12, fmaf(w, r22, mux2))) - xc;
        errsum += sqrtf(fmaf(z0, z0, fmaf(z1, z1, z2*z2)));
    }
    if (tid >= nb) errsum = 0.0f;

    // ---- single-wave reduction: shuffles, then one atomic per block ----
    #pragma unroll
    for (int off = 32; off > 0; off >>= 1) errsum += __shfl_down(errsum, off, 64);
    if (tid == 0) atomicAdd(out, errsum * inv_total);
}

extern "C" void kernel_launch(void* const* d_in, const int* in_sizes, int n_in,
                              void* d_out, int out_size, void* d_ws, size_t ws_size,
                              hipStream_t stream)
{
    const float* pred = (const float*)d_in[0];   // pred_kp3d   [B,21,3] f32
    const float* targ = (const float*)d_in[1];   // target_kp3d [B,21,3] f32
    float* out = (float*)d_out;

    int B = in_sizes[0] / FLB;
    float inv_total = 1.0f / ((float)B * (float)NPTS);

    pa_init<<<1, 64, 0, stream>>>(out);   // d_out is poisoned 0xAA before every launch
    int grid = (B + BPB - 1) / BPB;
    pa_mpjpe<<<grid, THREADS, 0, stream>>>(pred, targ, out, B, inv_total);
}

// Round 3
// 149.468 us; speedup vs baseline: 1.3230x; 1.3230x over previous
//
#include <hip/hip_runtime.h>
#include <math.h>

#define NPTS 21
#define FLB  63           // floats per batch per tensor (21*3)
#define BPB  128          // batches per block = one batch per thread
#define THREADS 128       // 2 waves -> real __syncthreads fence around async loads
#define NVEC (BPB * FLB / 4)      // 2016 float4s per tensor-chunk
#define FULL_ROUNDS (NVEC / THREADS)   // 15
#define TAIL_LANES  (NVEC % THREADS)   // 96

// direct global->LDS DMA, 16B per lane; lptr must be wave-uniform (HW adds lane*16)
__device__ __forceinline__ void async_cp16(const float* g, float* l) {
    __builtin_amdgcn_global_load_lds(
        (__attribute__((address_space(1))) void*)g,
        (__attribute__((address_space(3))) void*)l,
        16, 0, 0);
}

__global__ __launch_bounds__(THREADS)
void pa_mpjpe(const float* __restrict__ pred,
              const float* __restrict__ targ,
              float* __restrict__ ws,
              int B)
{
    // stride-63 per-thread layout: odd stride -> at most 2-way bank aliasing (free)
    __shared__ __align__(16) float sbuf[BPB * FLB];   // 32256 B -> 5 blocks/CU
    __shared__ float swsum[THREADS / 64];

    const int tid  = threadIdx.x;
    const int lane_u = tid & ~63;                     // wave-uniform lane base (0 or 64)
    const int b0   = blockIdx.x * BPB;

    // ---- stage PRED chunk: 16 async DMA loads, fully unrolled, one drain ----
    {
        const float* gp = pred + (size_t)b0 * FLB;
        #pragma unroll
        for (int j = 0; j < FULL_ROUNDS; ++j)
            async_cp16(gp + 4 * (j * THREADS + tid), sbuf + 4 * (j * THREADS + lane_u));
        if (tid < TAIL_LANES)
            async_cp16(gp + 4 * (FULL_ROUNDS * THREADS + tid),
                       sbuf + 4 * (FULL_ROUNDS * THREADS + lane_u));
    }
    __builtin_amdgcn_s_waitcnt(0x0F70);   // vmcnt(0), expcnt/lgkmcnt ignored
    __syncthreads();

    // ---- pred -> registers, accumulate raw moments ----
    float y[NPTS][3];
    float sy0 = 0.f, sy1 = 0.f, sy2 = 0.f, syy = 0.f;
    const int base = tid * FLB;
    #pragma unroll
    for (int n = 0; n < NPTS; ++n) {
        float a = sbuf[base + 3*n + 0];
        float b = sbuf[base + 3*n + 1];
        float c = sbuf[base + 3*n + 2];
        y[n][0] = a; y[n][1] = b; y[n][2] = c;
        sy0 += a; sy1 += b; sy2 += c;
        syy = fmaf(a, a, fmaf(b, b, fmaf(c, c, syy)));
    }
    __syncthreads();   // all waves done reading pred before targ overwrites sbuf

    // ---- stage TARG chunk into the SAME LDS buffer (async DMA) ----
    {
        const float* gt = targ + (size_t)b0 * FLB;
        #pragma unroll
        for (int j = 0; j < FULL_ROUNDS; ++j)
            async_cp16(gt + 4 * (j * THREADS + tid), sbuf + 4 * (j * THREADS + lane_u));
        if (tid < TAIL_LANES)
            async_cp16(gt + 4 * (FULL_ROUNDS * THREADS + tid),
                       sbuf + 4 * (FULL_ROUNDS * THREADS + lane_u));
    }
    __builtin_amdgcn_s_waitcnt(0x0F70);
    __syncthreads();

    // ---- targ stats + raw cross-covariance M[i][j] = sum_n x_i * y_j ----
    float sx0 = 0.f, sx1 = 0.f, sx2 = 0.f;
    float m00=0,m01=0,m02=0, m10=0,m11=0,m12=0, m20=0,m21=0,m22=0;
    #pragma unroll
    for (int n = 0; n < NPTS; ++n) {
        float a = sbuf[base + 3*n + 0];
        float b = sbuf[base + 3*n + 1];
        float c = sbuf[base + 3*n + 2];
        sx0 += a; sx1 += b; sx2 += c;
        float u = y[n][0], v = y[n][1], w = y[n][2];
        m00 = fmaf(a,u,m00); m01 = fmaf(a,v,m01); m02 = fmaf(a,w,m02);
        m10 = fmaf(b,u,m10); m11 = fmaf(b,v,m11); m12 = fmaf(b,w,m12);
        m20 = fmaf(c,u,m20); m21 = fmaf(c,v,m21); m22 = fmaf(c,w,m22);
    }

    const float invN = 1.0f / (float)NPTS;
    float mux0 = sx0*invN, mux1 = sx1*invN, mux2 = sx2*invN;
    float muy0 = sy0*invN, muy1 = sy1*invN, muy2 = sy2*invN;
    float ny2  = syy - (sy0*sy0 + sy1*sy1 + sy2*sy2) * invN;   // ||Y0||_F^2
    // centered cross-cov (rows: targ dims i, cols: pred dims j)
    float c00 = m00 - sx0*sy0*invN, c01 = m01 - sx0*sy1*invN, c02 = m02 - sx0*sy2*invN;
    float c10 = m10 - sx1*sy0*invN, c11 = m11 - sx1*sy1*invN, c12 = m12 - sx1*sy2*invN;
    float c20 = m20 - sx2*sy0*invN, c21 = m21 - sx2*sy1*invN, c22 = m22 - sx2*sy2*invN;

    // ---- orthogonal polar factor of A = Mc^T via det-scaled Newton ----
    // A = V S U^T => polar Q = V U^T (reference's rotation, reflection allowed),
    // tr(P) = sum of singular values = <Q, A>_F.  Scale-invariant: skip norms.
    float q00=c00, q01=c10, q02=c20,
          q10=c01, q11=c11, q12=c21,
          q20=c02, q21=c12, q22=c22;
    #pragma unroll
    for (int it = 0; it < 8; ++it) {
        float C00 = q11*q22 - q12*q21;
        float C01 = q12*q20 - q10*q22;
        float C02 = q10*q21 - q11*q20;
        float C10 = q02*q21 - q01*q22;
        float C11 = q00*q22 - q02*q20;
        float C12 = q01*q20 - q00*q21;
        float C20 = q01*q12 - q02*q11;
        float C21 = q02*q10 - q00*q12;
        float C22 = q00*q11 - q01*q10;
        float det = q00*C00 + q01*C01 + q02*C02;
        float ad  = fmaxf(fabsf(det), 1e-30f);
        float sdet = copysignf(ad, det);
        float g  = __expf(0.333333333f * __logf(ad));   // |det|^{1/3}
        float ha = 0.5f / g;                            // 0.5 * gamma
        float hb = 0.5f * g / sdet;                     // 0.5 * gamma^{-1} / det
        q00 = ha*q00 + hb*C00; q01 = ha*q01 + hb*C01; q02 = ha*q02 + hb*C02;
        q10 = ha*q10 + hb*C10; q11 = ha*q11 + hb*C11; q12 = ha*q12 + hb*C12;
        q20 = ha*q20 + hb*C20; q21 = ha*q21 + hb*C21; q22 = ha*q22 + hb*C22;
    }

    // tr(P) = <Q, A>_F with A = Mc^T  (sum of singular values of Mc)
    float trP = q00*c00 + q01*c10 + q02*c20
              + q10*c01 + q11*c11 + q12*c21
              + q20*c02 + q21*c12 + q22*c22;
    // Z_j = (trP/||Y0||^2) * sum_i (y_i - muY_i) Q_ij + muX_j   (normX cancels)
    float k = trP / ny2;
    float r00=k*q00, r01=k*q01, r02=k*q02;
    float r10=k*q10, r11=k*q11, r12=k*q12;
    float r20=k*q20, r21=k*q21, r22=k*q22;

    // ---- per-joint error (targ still in LDS) ----
    float errsum = 0.0f;
    #pragma unroll
    for (int n = 0; n < NPTS; ++n) {
        float xa = sbuf[base + 3*n + 0];
        float xb = sbuf[base + 3*n + 1];
        float xc = sbuf[base + 3*n + 2];
        float u = y[n][0] - muy0, v = y[n][1] - muy1, w = y[n][2] - muy2;
        float z0 = fmaf(u, r00, fmaf(v, r10, fmaf(w, r20, mux0))) - xa;
        float z1 = fmaf(u, r01, fmaf(v, r11, fmaf(w, r21, mux1))) - xb;
        float z2 = fmaf(u, r02, fmaf(v, r12, fmaf(w, r22, mux2))) - xc;
        errsum += sqrtf(fmaf(z0, z0, fmaf(z1, z1, z2*z2)));
    }

    // ---- block reduction -> ONE plain store per block (no atomics) ----
    #pragma unroll
    for (int off = 32; off > 0; off >>= 1) errsum += __shfl_down(errsum, off, 64);
    if ((tid & 63) == 0) swsum[tid >> 6] = errsum;
    __syncthreads();
    if (tid == 0) ws[blockIdx.x] = swsum[0] + swsum[1];
}

// single block: reduce the 2048 per-block partials, write the final mean
__global__ __launch_bounds__(256)
void pa_reduce(const float* __restrict__ ws, float* __restrict__ out,
               int nblk, float inv_total)
{
    __shared__ float sw[4];
    float s = 0.0f;
    for (int i = threadIdx.x; i < nblk; i += 256) s += ws[i];
    #pragma unroll
    for (int off = 32; off > 0; off >>= 1) s += __shfl_down(s, off, 64);
    if ((threadIdx.x & 63) == 0) sw[threadIdx.x >> 6] = s;
    __syncthreads();
    if (threadIdx.x == 0)
        out[0] = (sw[0] + sw[1] + sw[2] + sw[3]) * inv_total;
}

extern "C" void kernel_launch(void* const* d_in, const int* in_sizes, int n_in,
                              void* d_out, int out_size, void* d_ws, size_t ws_size,
                              hipStream_t stream)
{
    const float* pred = (const float*)d_in[0];   // pred_kp3d   [B,21,3] f32
    const float* targ = (const float*)d_in[1];   // target_kp3d [B,21,3] f32
    float* out = (float*)d_out;
    float* ws  = (float*)d_ws;

    int B = in_sizes[0] / FLB;                   // 262144 (divisible by BPB)
    int grid = (B + BPB - 1) / BPB;              // 2048
    float inv_total = 1.0f / ((float)B * (float)NPTS);

    pa_mpjpe<<<grid, THREADS, 0, stream>>>(pred, targ, ws, B);
    pa_reduce<<<1, 256, 0, stream>>>(ws, out, grid, inv_total);
}